// Round 5
// baseline (98.793 us; speedup 1.0000x reference)
//
#include <hip/hip_runtime.h>
#include <math.h>

// out[n,o] = exp(A)*cos(B)
//   A = sum_i ln(R)*Wr - K*Wi ;  B = sum_i ln(R)*Wi + K*Wr
//   R = 1 + g*(|x|-1) = g*|x| + (1-g),  K = pi*(x<0)*g,  g = clip(G,0,1)
// n=8192, i=o=128.
//
// R15b: identical theory/structure to R15 (round 4 was an infra failure,
// container never ran the bench). Lane-remap to kill the LDS broadcast wall.
// R14 established: (1) the 256MiB ws fill (~41us) is UNCONDITIONAL harness
// overhead -> using ws is free; (2) main ~= 40-45us in all rounds. Serial
// pipe sum of old structure: VALU 5 + TRANS 7 + LDS-broadcast 15-20 (4x
// broadcast ds_read_b128/wave-iter, 1KB writeback each) + VMEM 7 ~= 39us
// ~= measured -> convoyed pipes, LDS-broadcast largest term.
// Fix: x-row data lives in REGISTERS (wave preloads its 8 rows x 32-i slice
// of raw x into 4 lane-striped VGPRs; per i-iter v_readlane extracts the 8
// wave-uniform row values -> uniform abs/sign -> scalar operands). Weights
// stay per-lane coalesced VMEM (24B/lane/i-iter), precomputed in ws as
// (ln2*wr, ln2*wi, g, 1-g) + (-pi*g*wi, pi*g*wr). NO LDS in main loop.
// Cell = 1 fma + 1 v_log + 2 v_pk_fma_f32. i split 4-way across waves
// (32KB LDS q-reduce epilogue), o split 2-way.
// Geometry: 1024 blocks x 512 thr (8 waves: w = iq*2 + h), 8 rows/block,
// launch_bounds(512,8) -> 64-VGPR cap (est ~50), 4 blocks/CU, 8 waves/SIMD.
// Floor: VALU ~9us, TRANS ~6.8 (overlap), VMEM-return ~10 (overlap) ->
// main ~13-16us. Predict total 85.6 -> 58-65us.

#define NROWS 8192
#define DIM   128
#define RPB   8
#define NT    512
#define PI_F  3.14159265358979323846f
#define LN2_F 0.69314718055994530942f

typedef float v2f __attribute__((ext_vector_type(2)));

static __device__ __forceinline__ v2f vfma2(v2f a, v2f b, v2f c) {
    return __builtin_elementwise_fma(a, b, c);
}

// prep: 64 blocks x 256. wq[i*128+o] = (ln2*wr, ln2*wi, g, 1-g)
//                        wb[i*128+o] = (-pi*g*wi, pi*g*wr)
__global__ __launch_bounds__(256) void prep(
    const float* __restrict__ Wr, const float* __restrict__ Wi,
    const float* __restrict__ G,
    float4* __restrict__ wq, float2* __restrict__ wb)
{
    int t = blockIdx.x * 256 + threadIdx.x;
    if (t < DIM * DIM) {
        float g  = fminf(fmaxf(G[t], 0.0f), 1.0f);
        float wr = Wr[t], wi = Wi[t];
        wq[t] = make_float4(LN2_F * wr, LN2_F * wi, g, 1.0f - g);
        wb[t] = make_float2(-PI_F * g * wi, PI_F * g * wr);
    }
}

__global__ __launch_bounds__(NT, 8) void main_kernel(
    const float* __restrict__ x, const float4* __restrict__ wq,
    const float2* __restrict__ wb, float* __restrict__ out)
{
    __shared__ float2 P[8][RPB][64];      // [wave][row][lane] partials, 32 KB

    const int tid   = threadIdx.x;
    const int lane  = tid & 63;
    const int w     = tid >> 6;           // 8 waves
    const int h     = w & 1;              // o-half 0..1
    const int iq    = w >> 1;             // i-quarter 0..3
    const int i0    = iq * 32;
    const int nbase = blockIdx.x * RPB;
    const int o     = h * 64 + lane;

    // x preload: vx[k] holds (row = nbase + 2k + (lane>>5), i = i0 + (lane&31)).
    // readlane(vx[r>>1], (r&1)*32 + ii) == x[nbase+r][i0+ii], wave-uniform.
    float vx[4];
#pragma unroll
    for (int k = 0; k < 4; ++k)
        vx[k] = x[(size_t)(nbase + 2 * k + (lane >> 5)) * DIM + i0 + (lane & 31)];

    v2f acc[RPB];                         // acc[r] = (A_r, B_r) for this o
#pragma unroll
    for (int r = 0; r < RPB; ++r) acc[r] = (v2f){0.f, 0.f};

    const float4* wqp = wq + (size_t)i0 * DIM + o;
    const float2* wbp = wb + (size_t)i0 * DIM + o;

    // Software pipeline: weights for iter ii prefetched at ii-1 (wrap = reload).
    float4 wqc = wqp[0];
    float2 wbc = wbp[0];

#pragma unroll 2
    for (int ii = 0; ii < 32; ++ii) {
        const int nx = (ii + 1) & 31;
        float4 wqn = wqp[(size_t)nx * DIM];
        float2 wbn = wbp[(size_t)nx * DIM];

        const float g  = wqc.z;
        const float hh = wqc.w;                 // 1-g
        const v2f   w2  = {wqc.x, wqc.y};       // (ln2*wr, ln2*wi)
        const v2f   pg2 = {wbc.x, wbc.y};       // (-pi*g*wi, pi*g*wr)

#pragma unroll
        for (int r = 0; r < RPB; ++r) {
            // Wave-uniform row value via readlane (no memory pipe).
            int   xi = __builtin_amdgcn_readlane(__float_as_int(vx[r >> 1]),
                                                 (r & 1) * 32 + ii);
            float xr = __int_as_float(xi);
            float ax = fabsf(xr);
            float sf = (xr < 0.0f) ? 1.0f : 0.0f;
            float t  = fmaf(g, ax, hh);                  // R
            float l  = __log2f(t);
            // (A,B) += l*(ln2wr, ln2wi) + sf*(-pi g wi, pi g wr)
            acc[r] = vfma2((v2f){l, l}, w2,
                           vfma2((v2f){sf, sf}, pg2, acc[r]));
        }
        wqc = wqn; wbc = wbn;
    }

    // Epilogue: iq-reduce across the 4 waves sharing (h, rows).
#pragma unroll
    for (int r = 0; r < RPB; ++r)
        P[w][r][lane] = make_float2(acc[r].x, acc[r].y);
    __syncthreads();

#pragma unroll
    for (int cc = 0; cc < 2; ++cc) {
        const int c  = tid + cc * NT;          // 0..1023 = (row, o) cells
        const int r  = c >> 7;
        const int oo = c & (DIM - 1);
        const int h2 = oo >> 6, ol = oo & 63;
        float A = 0.f, B = 0.f;
#pragma unroll
        for (int q2 = 0; q2 < 4; ++q2) {
            float2 p = P[q2 * 2 + h2][r][ol];
            A += p.x; B += p.y;
        }
        out[(size_t)(nbase + r) * DIM + oo] = __expf(A) * __cosf(B);
    }
}

// Fallback (no workspace): R14's verified LDS-plane kernel.
__global__ __launch_bounds__(NT, 4) void fb_kernel(
    const float* __restrict__ x,
    const float* __restrict__ Wr, const float* __restrict__ Wi,
    const float* __restrict__ G, float* __restrict__ out)
{
    __shared__ float sbuf[4 * RPB * DIM];
    float* am1p = sbuf;
    float* psp  = sbuf + DIM * RPB;

    const int tid   = threadIdx.x;
    const int o     = tid & (DIM - 1);
    const int q     = tid >> 7;
    const int nbase = blockIdx.x * RPB;

    {
        const float* xb = x + (size_t)nbase * DIM;
        float2 v = ((const float2*)xb)[tid];
        int e = tid * 2;
        int i = e & (DIM - 1), r = e >> 7;
        am1p[i * RPB + r]       = fabsf(v.x) - 1.0f;
        am1p[(i + 1) * RPB + r] = fabsf(v.y) - 1.0f;
        psp[i * RPB + r]        = (v.x < 0.0f) ? PI_F : 0.0f;
        psp[(i + 1) * RPB + r]  = (v.y < 0.0f) ? PI_F : 0.0f;
    }
    __syncthreads();

    v2f accA[4], accB[4];
#pragma unroll
    for (int p = 0; p < 4; ++p) { accA[p] = (v2f){0.f, 0.f}; accB[p] = (v2f){0.f, 0.f}; }

    const int ibase = q * 32;
#pragma unroll 4
    for (int ii = 0; ii < 32; ++ii) {
        const int i = ibase + ii;
        const int wi_idx = i * DIM + o;
        float g   = fminf(fmaxf(G[wi_idx], 0.0f), 1.0f);
        float wrl = LN2_F * Wr[wi_idx];
        float wil = LN2_F * Wi[wi_idx];
        const float ngwi = -g * (wil * (1.0f / LN2_F));
        const float gwr  =  g * (wrl * (1.0f / LN2_F));
        const v2f gg2 = {g, g}, wrl2 = {wrl, wrl}, wil2 = {wil, wil};
        const v2f ngwi2 = {ngwi, ngwi}, gwr2 = {gwr, gwr}, one2 = {1.f, 1.f};

        const float4* a4 = (const float4*)(am1p + i * RPB);
        const float4* p4 = (const float4*)(psp  + i * RPB);
        float4 a03 = a4[0], a47 = a4[1];
        float4 s03 = p4[0], s47 = p4[1];

#define ROWPAIR(mx, my, sx, sy, idx)                                        \
        do {                                                                \
            v2f t2 = vfma2((v2f){mx, my}, gg2, one2);                       \
            v2f l2 = { __log2f(t2.x), __log2f(t2.y) };                      \
            v2f s2 = {sx, sy};                                              \
            accA[idx] = vfma2(l2, wrl2, vfma2(s2, ngwi2, accA[idx]));       \
            accB[idx] = vfma2(l2, wil2, vfma2(s2, gwr2,  accB[idx]));       \
        } while (0)

        ROWPAIR(a03.x, a03.y, s03.x, s03.y, 0);
        ROWPAIR(a03.z, a03.w, s03.z, s03.w, 1);
        ROWPAIR(a47.x, a47.y, s47.x, s47.y, 2);
        ROWPAIR(a47.z, a47.w, s47.z, s47.w, 3);
#undef ROWPAIR
    }

    float* pP = sbuf;
    const int c = tid * 2;
    const int r = c >> 7, oo = c & (DIM - 1);

    __syncthreads();
#pragma unroll
    for (int p = 0; p < 4; ++p) {
        pP[q * (RPB * DIM) + (2 * p) * DIM + o]     = accA[p].x;
        pP[q * (RPB * DIM) + (2 * p + 1) * DIM + o] = accA[p].y;
    }
    __syncthreads();
    v2f A = {0.f, 0.f};
#pragma unroll
    for (int qq = 0; qq < 4; ++qq)
        A += *(const v2f*)&pP[qq * (RPB * DIM) + r * DIM + oo];
    __syncthreads();
#pragma unroll
    for (int p = 0; p < 4; ++p) {
        pP[q * (RPB * DIM) + (2 * p) * DIM + o]     = accB[p].x;
        pP[q * (RPB * DIM) + (2 * p + 1) * DIM + o] = accB[p].y;
    }
    __syncthreads();
    v2f B = {0.f, 0.f};
#pragma unroll
    for (int qq = 0; qq < 4; ++qq)
        B += *(const v2f*)&pP[qq * (RPB * DIM) + r * DIM + oo];

    float2 res;
    res.x = __expf(A.x) * __cosf(B.x);
    res.y = __expf(A.y) * __cosf(B.y);
    *(float2*)&out[(size_t)(nbase + r) * DIM + oo] = res;
}

extern "C" void kernel_launch(void* const* d_in, const int* in_sizes, int n_in,
                              void* d_out, int out_size, void* d_ws, size_t ws_size,
                              hipStream_t stream) {
    const float* x  = (const float*)d_in[0];
    const float* Wr = (const float*)d_in[1];
    const float* Wi = (const float*)d_in[2];
    const float* G  = (const float*)d_in[3];
    float* out = (float*)d_out;

    const size_t wq_bytes = (size_t)DIM * DIM * sizeof(float4);   // 256 KB
    const size_t wb_bytes = (size_t)DIM * DIM * sizeof(float2);   // 128 KB
    if (ws_size >= wq_bytes + wb_bytes) {
        float4* wq = (float4*)d_ws;
        float2* wb = (float2*)((char*)d_ws + wq_bytes);
        prep<<<(DIM * DIM + 255) / 256, 256, 0, stream>>>(Wr, Wi, G, wq, wb);
        main_kernel<<<NROWS / RPB, NT, 0, stream>>>(x, wq, wb, out);
    } else {
        fb_kernel<<<NROWS / RPB, NT, 0, stream>>>(x, Wr, Wi, G, out);
    }
}

// Round 6
// 88.257 us; speedup vs baseline: 1.1194x; 1.1194x over previous
//
#include <hip/hip_runtime.h>
#include <math.h>

// out[n,o] = exp(A)*cos(B)
//   A = sum_i ln(R)*Wr - K*Wi ;  B = sum_i ln(R)*Wi + K*Wr
//   R = 1 + g*(|x|-1),  K = pi*(x<0)*g,  g = clip(G,0,1)
// n=8192, i=o=128.
//
// R16: RPB 8->16 + depth-2 weight pipeline + row-pair packing restored.
// R15b (registers+readlane, zero LDS in loop) measured main=43.2us,
// VALUBusy=71%, Occ=51% -> SAME ~40-43 as the LDS-plane variants: the
// LDS-broadcast-writeback theory is DEAD. Remaining suspects, all hit here:
// (1) VALU bloat: acc-packed layout splats {l,l},{sf,sf} per CELL (~9
//     instr/cell-row). Row-pair packing splats weights per ITER: at RPB=16
//     the 5 splats amortize over 8 pairs -> ~3.8 VALU/cell.
// (2) weight stream: RPB=8 re-reads the 384KB weight image 1024x = 393MB
//     L2 traffic, prefetch depth 1 (~130cy) < L2 latency (~250cy) ->
//     per-iter exposed stalls. RPB=16 halves traffic; depth-2 covers it.
// Floor: VALU ~6.8us/SIMD issue + trans 3.4 + L1-return 5.1 -> main 10-12.
// Predict main 43->15-25us, total ~62-72us (fill 41 is unconditional).
// Geometry: 512 blocks x 512 thr (8 waves; w= iq*2+h, h=o-half, iq=
// i-quarter), 16 rows/block, LB(512,4) ~128 VGPR cap, 32KB LDS
// (16KB planes -> 32KB epilogue overlay).

#define NROWS 8192
#define DIM   128
#define RPB   16
#define NT    512
#define PI_F  3.14159265358979323846f
#define LN2_F 0.69314718055994530942f

typedef float v2f __attribute__((ext_vector_type(2)));

static __device__ __forceinline__ v2f vfma2(v2f a, v2f b, v2f c) {
    return __builtin_elementwise_fma(a, b, c);
}

// prep: 64 blocks x 256. wq[i*128+o] = (ln2*wr, ln2*wi, g, unused)
//                        wb[i*128+o] = (-pi*g*wi, pi*g*wr)
__global__ __launch_bounds__(256) void prep(
    const float* __restrict__ Wr, const float* __restrict__ Wi,
    const float* __restrict__ G,
    float4* __restrict__ wq, float2* __restrict__ wb)
{
    int t = blockIdx.x * 256 + threadIdx.x;
    if (t < DIM * DIM) {
        float g  = fminf(fmaxf(G[t], 0.0f), 1.0f);
        float wr = Wr[t], wi = Wi[t];
        wq[t] = make_float4(LN2_F * wr, LN2_F * wi, g, 0.0f);
        wb[t] = make_float2(-PI_F * g * wi, PI_F * g * wr);
    }
}

__global__ __launch_bounds__(NT, 4) void main_kernel(
    const float* __restrict__ x, const float4* __restrict__ wq,
    const float2* __restrict__ wb, float* __restrict__ out)
{
    // 32 KB. Main loop: am1 + sf planes [DIM][RPB] (16 KB).
    // Epilogue overlay: partials [4][RPB][DIM] (32 KB), A then B.
    __shared__ float sbuf[4 * RPB * DIM];
    float* am1p = sbuf;               // [DIM][RPB]
    float* sfp  = sbuf + DIM * RPB;   // [DIM][RPB]  (1.0 where x<0 else 0.0)

    const int tid   = threadIdx.x;
    const int lane  = tid & 63;
    const int w     = tid >> 6;           // 8 waves
    const int h     = w & 1;              // o-half
    const int iq    = w >> 1;             // i-quarter
    const int i0    = iq * 32;
    const int o     = h * 64 + lane;
    const int nbase = blockIdx.x * RPB;

    // Stage x tile (16 rows x 128 i = 2048 floats): float4 coalesced.
    {
        const float4* xb = (const float4*)(x + (size_t)nbase * DIM);
        float4 v = xb[tid];
        int e = tid * 4;
        int i = e & (DIM - 1), r = e >> 7;    // float4 stays in row r (0..15)
        float vv[4] = {v.x, v.y, v.z, v.w};
#pragma unroll
        for (int k = 0; k < 4; ++k) {
            am1p[(i + k) * RPB + r] = fabsf(vv[k]) - 1.0f;
            sfp[(i + k) * RPB + r]  = (vv[k] < 0.0f) ? 1.0f : 0.0f;
        }
    }
    __syncthreads();

    v2f accA[8], accB[8];                 // row-pairs 0..7 (rows 2p, 2p+1)
#pragma unroll
    for (int p = 0; p < 8; ++p) { accA[p] = (v2f){0.f, 0.f}; accB[p] = (v2f){0.f, 0.f}; }

    const float4* wqp = wq + (size_t)i0 * DIM + o;
    const float2* wbp = wb + (size_t)i0 * DIM + o;

    // Depth-2 weight pipeline: iter ii uses slot loaded 2 iters ago.
    float4 wq0 = wqp[0],   wq1 = wqp[DIM];
    float2 wb0 = wbp[0],   wb1 = wbp[DIM];

#pragma unroll 2
    for (int ii = 0; ii < 32; ++ii) {
        const int p2 = (ii + 2) & 31;                // wraps, in-bounds
        float4 wqn = wqp[(size_t)p2 * DIM];
        float2 wbn = wbp[(size_t)p2 * DIM];

        const int i = i0 + ii;
        // 16 rows: 4+4 broadcast ds_read_b128 (issue early, lgkm covers).
        const float4* a4 = (const float4*)(am1p + i * RPB);
        const float4* s4 = (const float4*)(sfp  + i * RPB);
        float4 aA = a4[0], aB = a4[1], aC = a4[2], aD = a4[3];
        float4 sA = s4[0], sB = s4[1], sC = s4[2], sD = s4[3];

        const float g    = wq0.z;
        const float wrl  = wq0.x, wil = wq0.y;
        const float ngwi = wb0.x, pgwr = wb0.y;      // -pi*g*wi, pi*g*wr
        const v2f gg2   = {g, g};
        const v2f wrl2  = {wrl, wrl};
        const v2f wil2  = {wil, wil};
        const v2f ngwi2 = {ngwi, ngwi};
        const v2f pgwr2 = {pgwr, pgwr};
        const v2f one2  = {1.0f, 1.0f};

#define ROWPAIR(mx, my, sx, sy, idx)                                        \
        do {                                                                \
            v2f t2 = vfma2((v2f){mx, my}, gg2, one2);                       \
            v2f l2 = { __log2f(t2.x), __log2f(t2.y) };                      \
            v2f s2 = {sx, sy};                                              \
            accA[idx] = vfma2(l2, wrl2, vfma2(s2, ngwi2, accA[idx]));       \
            accB[idx] = vfma2(l2, wil2, vfma2(s2, pgwr2, accB[idx]));       \
        } while (0)

        ROWPAIR(aA.x, aA.y, sA.x, sA.y, 0);
        ROWPAIR(aA.z, aA.w, sA.z, sA.w, 1);
        ROWPAIR(aB.x, aB.y, sB.x, sB.y, 2);
        ROWPAIR(aB.z, aB.w, sB.z, sB.w, 3);
        ROWPAIR(aC.x, aC.y, sC.x, sC.y, 4);
        ROWPAIR(aC.z, aC.w, sC.z, sC.w, 5);
        ROWPAIR(aD.x, aD.y, sD.x, sD.y, 6);
        ROWPAIR(aD.z, aD.w, sD.z, sD.w, 7);
#undef ROWPAIR

        wq0 = wq1; wq1 = wqn;
        wb0 = wb1; wb1 = wbn;
    }

    // Epilogue: iq-reduce via the full 32 KB buffer, A then B.
    float* pP = sbuf;                        // [4][RPB][DIM]
    const int c4 = tid * 4;                  // 4 cells per thread

    __syncthreads();   // all waves done reading planes
#pragma unroll
    for (int p = 0; p < 8; ++p) {
        pP[iq * (RPB * DIM) + (2 * p) * DIM + o]     = accA[p].x;
        pP[iq * (RPB * DIM) + (2 * p + 1) * DIM + o] = accA[p].y;
    }
    __syncthreads();
    float4 A4 = make_float4(0.f, 0.f, 0.f, 0.f);
#pragma unroll
    for (int q2 = 0; q2 < 4; ++q2) {
        float4 t = *(const float4*)&pP[q2 * (RPB * DIM) + c4];
        A4.x += t.x; A4.y += t.y; A4.z += t.z; A4.w += t.w;
    }
    __syncthreads();   // before overwriting with B partials
#pragma unroll
    for (int p = 0; p < 8; ++p) {
        pP[iq * (RPB * DIM) + (2 * p) * DIM + o]     = accB[p].x;
        pP[iq * (RPB * DIM) + (2 * p + 1) * DIM + o] = accB[p].y;
    }
    __syncthreads();
    float4 B4 = make_float4(0.f, 0.f, 0.f, 0.f);
#pragma unroll
    for (int q2 = 0; q2 < 4; ++q2) {
        float4 t = *(const float4*)&pP[q2 * (RPB * DIM) + c4];
        B4.x += t.x; B4.y += t.y; B4.z += t.z; B4.w += t.w;
    }

    float4 res;
    res.x = __expf(A4.x) * __cosf(B4.x);
    res.y = __expf(A4.y) * __cosf(B4.y);
    res.z = __expf(A4.z) * __cosf(B4.z);
    res.w = __expf(A4.w) * __cosf(B4.w);
    ((float4*)(out + (size_t)nbase * DIM))[tid] = res;   // coalesced dwordx4
}

// Fallback (no workspace): R14's verified LDS-plane kernel (RPB=8 geometry).
__global__ __launch_bounds__(NT, 4) void fb_kernel(
    const float* __restrict__ x,
    const float* __restrict__ Wr, const float* __restrict__ Wi,
    const float* __restrict__ G, float* __restrict__ out)
{
    __shared__ float sbuf[4 * 8 * DIM];
    float* am1p = sbuf;
    float* psp  = sbuf + DIM * 8;

    const int tid   = threadIdx.x;
    const int o     = tid & (DIM - 1);
    const int q     = tid >> 7;
    const int nbase = blockIdx.x * 8;

    {
        const float* xb = x + (size_t)nbase * DIM;
        float2 v = ((const float2*)xb)[tid];
        int e = tid * 2;
        int i = e & (DIM - 1), r = e >> 7;
        am1p[i * 8 + r]       = fabsf(v.x) - 1.0f;
        am1p[(i + 1) * 8 + r] = fabsf(v.y) - 1.0f;
        psp[i * 8 + r]        = (v.x < 0.0f) ? PI_F : 0.0f;
        psp[(i + 1) * 8 + r]  = (v.y < 0.0f) ? PI_F : 0.0f;
    }
    __syncthreads();

    v2f accA[4], accB[4];
#pragma unroll
    for (int p = 0; p < 4; ++p) { accA[p] = (v2f){0.f, 0.f}; accB[p] = (v2f){0.f, 0.f}; }

    const int ibase = q * 32;
#pragma unroll 4
    for (int ii = 0; ii < 32; ++ii) {
        const int i = ibase + ii;
        const int wi_idx = i * DIM + o;
        float g   = fminf(fmaxf(G[wi_idx], 0.0f), 1.0f);
        float wrl = LN2_F * Wr[wi_idx];
        float wil = LN2_F * Wi[wi_idx];
        const float ngwi = -g * (wil * (1.0f / LN2_F));
        const float gwr  =  g * (wrl * (1.0f / LN2_F));
        const v2f gg2 = {g, g}, wrl2 = {wrl, wrl}, wil2 = {wil, wil};
        const v2f ngwi2 = {ngwi, ngwi}, gwr2 = {gwr, gwr}, one2 = {1.f, 1.f};

        const float4* a4 = (const float4*)(am1p + i * 8);
        const float4* p4 = (const float4*)(psp  + i * 8);
        float4 a03 = a4[0], a47 = a4[1];
        float4 s03 = p4[0], s47 = p4[1];

#define ROWPAIR(mx, my, sx, sy, idx)                                        \
        do {                                                                \
            v2f t2 = vfma2((v2f){mx, my}, gg2, one2);                       \
            v2f l2 = { __log2f(t2.x), __log2f(t2.y) };                      \
            v2f s2 = {sx, sy};                                              \
            accA[idx] = vfma2(l2, wrl2, vfma2(s2, ngwi2, accA[idx]));       \
            accB[idx] = vfma2(l2, wil2, vfma2(s2, gwr2,  accB[idx]));       \
        } while (0)

        ROWPAIR(a03.x, a03.y, s03.x, s03.y, 0);
        ROWPAIR(a03.z, a03.w, s03.z, s03.w, 1);
        ROWPAIR(a47.x, a47.y, s47.x, s47.y, 2);
        ROWPAIR(a47.z, a47.w, s47.z, s47.w, 3);
#undef ROWPAIR
    }

    float* pP = sbuf;
    const int c = tid * 2;
    const int r = c >> 7, oo = c & (DIM - 1);

    __syncthreads();
#pragma unroll
    for (int p = 0; p < 4; ++p) {
        pP[q * (8 * DIM) + (2 * p) * DIM + o]     = accA[p].x;
        pP[q * (8 * DIM) + (2 * p + 1) * DIM + o] = accA[p].y;
    }
    __syncthreads();
    v2f A = {0.f, 0.f};
#pragma unroll
    for (int qq = 0; qq < 4; ++qq)
        A += *(const v2f*)&pP[qq * (8 * DIM) + r * DIM + oo];
    __syncthreads();
#pragma unroll
    for (int p = 0; p < 4; ++p) {
        pP[q * (8 * DIM) + (2 * p) * DIM + o]     = accB[p].x;
        pP[q * (8 * DIM) + (2 * p + 1) * DIM + o] = accB[p].y;
    }
    __syncthreads();
    v2f B = {0.f, 0.f};
#pragma unroll
    for (int qq = 0; qq < 4; ++qq)
        B += *(const v2f*)&pP[qq * (8 * DIM) + r * DIM + oo];

    float2 res;
    res.x = __expf(A.x) * __cosf(B.x);
    res.y = __expf(A.y) * __cosf(B.y);
    *(float2*)&out[(size_t)(nbase + r) * DIM + oo] = res;
}

extern "C" void kernel_launch(void* const* d_in, const int* in_sizes, int n_in,
                              void* d_out, int out_size, void* d_ws, size_t ws_size,
                              hipStream_t stream) {
    const float* x  = (const float*)d_in[0];
    const float* Wr = (const float*)d_in[1];
    const float* Wi = (const float*)d_in[2];
    const float* G  = (const float*)d_in[3];
    float* out = (float*)d_out;

    const size_t wq_bytes = (size_t)DIM * DIM * sizeof(float4);   // 256 KB
    const size_t wb_bytes = (size_t)DIM * DIM * sizeof(float2);   // 128 KB
    if (ws_size >= wq_bytes + wb_bytes) {
        float4* wq = (float4*)d_ws;
        float2* wb = (float2*)((char*)d_ws + wq_bytes);
        prep<<<(DIM * DIM + 255) / 256, 256, 0, stream>>>(Wr, Wi, G, wq, wb);
        main_kernel<<<NROWS / RPB, NT, 0, stream>>>(x, wq, wb, out);
    } else {
        fb_kernel<<<NROWS / 8, NT, 0, stream>>>(x, Wr, Wi, G, out);
    }
}